// Round 7
// baseline (324.213 us; speedup 1.0000x reference)
//
#include <hip/hip_runtime.h>
#include <stdint.h>

#define GRID_N (256*256*256)
#define MAXID 32
#define NCLS 13
#define NBINS ((MAXID+1)*NCLS)   // 429
#define PREP_BLOCKS 8192

// ws layout (bytes):
//   0     : int counts16[16][429]  (27456 B, zeroed via 32768-B memset)
//   32768 : uint seenArr[8192]     (32 KB, every entry written -- no zeroing)
//   65536 : int glut[34+35]
//   69632 : uint8 key8[GRID_N]     (16 MiB: bits 0..5 = keyid (id/32=wall/33=floor),
//                                   bit 6 = surface)
// key16 (uint16 per voxel, 32 MiB) lives in d_out[0:32MB] -- dead before k_nn
// overwrites all of d_out.

// ---------------------------------------------------------------- pass A
// PURE map (copy-shaped): no LDS, no atomics, no reductions. Decomposition
// experiment: does the 3-stream read reach copy BW (6.3 TB/s, m13) once all
// histogram side-effects are removed?  v = id | class<<5 | surface<<9.
__global__ __launch_bounds__(256) void k_prepA(const float* __restrict__ geo,
                                               const int* __restrict__ inst,
                                               const int* __restrict__ sem,
                                               uint16_t* __restrict__ key16) {
    int t = blockIdx.x * 256 + threadIdx.x;
    const int stride = PREP_BLOCKS * 256;          // 2,097,152
    const int4*   i4 = (const int4*)inst;
    const int4*   s4 = (const int4*)sem;
    const float4* g4 = (const float4*)geo;
    ushort4*      k4 = (ushort4*)key16;

    int idx0 = t, idx1 = t + stride;
    int4 a0 = i4[idx0], a1 = i4[idx1];
    int4 b0 = s4[idx0], b1 = s4[idx1];
    float4 g0 = g4[idx0], g1 = g4[idx1];

    ushort4 k0, k1;
    k0.x = (uint16_t)(a0.x | (b0.x << 5) | ((fabsf(g0.x) <= 1.5f) ? 512 : 0));
    k0.y = (uint16_t)(a0.y | (b0.y << 5) | ((fabsf(g0.y) <= 1.5f) ? 512 : 0));
    k0.z = (uint16_t)(a0.z | (b0.z << 5) | ((fabsf(g0.z) <= 1.5f) ? 512 : 0));
    k0.w = (uint16_t)(a0.w | (b0.w << 5) | ((fabsf(g0.w) <= 1.5f) ? 512 : 0));
    k1.x = (uint16_t)(a1.x | (b1.x << 5) | ((fabsf(g1.x) <= 1.5f) ? 512 : 0));
    k1.y = (uint16_t)(a1.y | (b1.y << 5) | ((fabsf(g1.y) <= 1.5f) ? 512 : 0));
    k1.z = (uint16_t)(a1.z | (b1.z << 5) | ((fabsf(g1.z) <= 1.5f) ? 512 : 0));
    k1.w = (uint16_t)(a1.w | (b1.w << 5) | ((fabsf(g1.w) <= 1.5f) ? 512 : 0));
    k4[idx0] = k0;
    k4[idx1] = k1;
}

// ---------------------------------------------------------------- pass B
// Small-footprint: read packed 32 MB, emit key8 (16 MB), conditional LDS
// histogram (only bins ever read: id in ids2d+1, class not in {0,10,11}),
// register seen-mask -> per-block plain store.
__global__ __launch_bounds__(256) void k_prepB(const uint16_t* __restrict__ key16,
                                               const int* __restrict__ ids2d, int n2d,
                                               int* __restrict__ counts16,
                                               unsigned int* __restrict__ seenArr,
                                               uint8_t* __restrict__ key8) {
    __shared__ int sh[4][NBINS];
    __shared__ unsigned int wseen[4];
    int t = threadIdx.x;
    for (int i = t; i < 4 * NBINS; i += 256) ((int*)sh)[i] = 0;
    __syncthreads();
    int* myh = sh[t >> 6];

    uint64_t m = 0;
    for (int k = 0; k < n2d; ++k) m |= 1ull << (ids2d[k] + 1);
    const unsigned int eligC = 0x13FE;   // classes not in {0,10,11}

    int idx = blockIdx.x * 256 + t;      // one ushort8 (8 voxels) per thread
    uint4 w = ((const uint4*)key16)[idx];
    unsigned int seen = 0;
    uint32_t out_lo = 0, out_hi = 0;
    uint32_t ws_[4] = {w.x, w.y, w.z, w.w};
    #pragma unroll
    for (int j = 0; j < 8; ++j) {
        uint32_t v = (ws_[j >> 1] >> ((j & 1) * 16)) & 0xFFFF;
        int id = v & 31, cls = (v >> 5) & 15, surf = (v >> 9) & 1;
        seen |= 1u << id;
        int kid = (cls == 11) ? 33 : ((cls == 10) ? 32 : id);
        uint32_t kb = (uint32_t)(kid | (surf << 6));
        if (j < 4) out_lo |= kb << (8 * j); else out_hi |= kb << (8 * (j - 4));
        if (((unsigned)(m >> id) & (eligC >> cls)) & 1)
            atomicAdd(&myh[id * NCLS + cls], 1);
    }
    uint2 o; o.x = out_lo; o.y = out_hi;
    ((uint2*)key8)[idx] = o;

    #pragma unroll
    for (int off = 32; off; off >>= 1) seen |= (unsigned int)__shfl_xor((int)seen, off);
    if ((t & 63) == 0) wseen[t >> 6] = seen;
    __syncthreads();
    if (t == 0)
        seenArr[blockIdx.x] = wseen[0] | wseen[1] | wseen[2] | wseen[3];

    int* dst = counts16 + (blockIdx.x & 15) * NBINS;
    for (int i = t; i < NBINS; i += 256) {
        int v = sh[0][i] + sh[1][i] + sh[2][i] + sh[3][i];
        if (v) atomicAdd(&dst[i], v);
    }
}

// ---------------------------------------------------------------- LUTs
__global__ __launch_bounds__(512) void k_luts(const int* __restrict__ counts16,
                                              const unsigned int* __restrict__ seenArr,
                                              const int* __restrict__ ids2d, int n2d,
                                              int* __restrict__ glut) {
    __shared__ int shc[NBINS];
    __shared__ int sem_s[35];
    __shared__ unsigned int wseen[8];
    int t = threadIdx.x;

    unsigned int s = 0;
    #pragma unroll
    for (int i = 0; i < 16; ++i) s |= seenArr[t + i * 512];
    #pragma unroll
    for (int o = 32; o; o >>= 1) s |= (unsigned int)__shfl_xor((int)s, o);
    if ((t & 63) == 0) wseen[t >> 6] = s;

    if (t < NBINS) {
        int acc = 0;
        #pragma unroll
        for (int c = 0; c < 16; ++c) acc += counts16[c * NBINS + t];
        shc[t] = acc;
    }
    __syncthreads();
    if (t < 64) {
        unsigned int seen = wseen[0] | wseen[1] | wseen[2] | wseen[3]
                          | wseen[4] | wseen[5] | wseen[6] | wseen[7];
        uint64_t m = 0;
        for (int k = 0; k < n2d; ++k) m |= 1ull << (ids2d[k] + 1);

        int in2d_t = (t <= MAXID) ? (int)((m >> t) & 1) : 0;
        int seen_t = (t < 32) ? (int)((seen >> t) & 1) : 0;
        int sel_t = 0;
        if (t <= MAXID) {
            int best = -2;
            for (int c = 0; c < NCLS; ++c) {
                int v = (c == 0 || c == 10 || c == 11) ? -1 : shc[t * NCLS + c];
                if (v > best) { best = v; sel_t = c; }
            }
        }
        int zero_present = ((seen & ~(unsigned int)m) != 0u) ? 1 : 0;
        int pres = (t >= 1 && in2d_t && seen_t) ? 1 : 0;
        unsigned long long pm = __ballot(pres);
        int rank_below = __popcll(pm & ((1ULL << t) - 1ULL));
        int pano_id = pres ? (rank_below + zero_present + 2) : 0;

        if (t < 35) sem_s[t] = (t == 1) ? 10 : ((t == 2) ? 11 : 0);
        if (pres) sem_s[pano_id] = sel_t;

        if (t < 32) glut[t] = (t == 0) ? 0 : pano_id;
        if (t == 32) glut[32] = 1;
        if (t == 33) glut[33] = 2;
        if (t < 35) glut[34 + t] = sem_s[t];
    }
}

// ---------------------------------------------------------------- pass 2
// Tile = 8x8 (x,y) x full 256 z-line. LDS rows: 13x13 (x,y halo [-3,+2])
// x 264 bytes (z = -4..259 wrapped). Byte = grid0 | surface<<7.
#define TX 8
#define TY 8
#define HR 13              // TX+5
#define NROWS (HR*HR)      // 169
#define ROWDW 66           // 264 B per row
#define NDW (NROWS*ROWDW)  // 11154

__global__ __launch_bounds__(512) void k_nn(const uint8_t* __restrict__ key,
                                            const int* __restrict__ glut,
                                            int* __restrict__ out_pano,
                                            int* __restrict__ out_sem) {
    __shared__ uint32_t shg[NDW];     // 44616 B
    __shared__ int lut[128];          // key(7b incl surface) -> grid0 | surface<<7
    __shared__ int slut[MAXID + 3];

    int t = threadIdx.x;
    if (t < 128) {
        int base = ((t & 63) <= 33) ? glut[t & 63] : 0;
        lut[t] = base | ((t & 64) << 1);
    } else if (t >= 128 && t < 128 + MAXID + 3) {
        slut[t - 128] = glut[34 + (t - 128)];
    }
    __syncthreads();

    int x0 = blockIdx.x * TX;
    int y0 = blockIdx.y * TY;

    const uint32_t* key32 = (const uint32_t*)key;
    for (int idx = t; idx < NDW; idx += 512) {
        int row = idx / ROWDW;
        int k = idx - row * ROWDW;
        int ix = row / HR;
        int iy = row - ix * HR;
        int gx = (x0 + ix - 3) & 255;
        int gy = (y0 + iy - 3) & 255;
        uint32_t w = key32[(gx << 14) | (gy << 6) | ((k - 1) & 63)];
        shg[idx] = (uint32_t)lut[w & 127]
                 | ((uint32_t)lut[(w >> 8) & 127] << 8)
                 | ((uint32_t)lut[(w >> 16) & 127] << 16)
                 | ((uint32_t)lut[(w >> 24) & 127] << 24);
    }
    __syncthreads();

    int zg = t & 63;          // z-group: z = 4*zg .. 4*zg+3
    int ty = t >> 6;          // 0..7
    int gy = y0 + ty;
    const uint64_t M6 = 0x00007F7F7F7F7F7FULL;

    for (int x = 0; x < TX; ++x) {
        int gx = x0 + x;
        int r0 = (x + 3) * HR + (ty + 3);
        uint32_t cw = shg[r0 * ROWDW + zg + 1];   // 4 center bytes (z=4zg..+3)
        int4 pano, semv;
        int pv[4];
        #pragma unroll
        for (int b = 0; b < 4; ++b) {
            int v = (cw >> (8 * b)) & 255;
            int p = v & 127;
            if (p == 0 && (v & 128)) {
                int z = 4 * zg + b;
                int label = 0;
                int j0 = z + 1;
                int a0 = j0 >> 2, off = j0 & 3;
                for (int dxi = 0; dxi < 6 && !label; ++dxi) {
                    int rb = ((x + dxi) * HR + ty) * ROWDW + a0;
                    for (int dyi = 0; dyi < 6; ++dyi) {
                        int a = rb + dyi * ROWDW;
                        uint32_t d0 = shg[a], d1 = shg[a + 1], d2 = shg[a + 2];
                        uint64_t lo = (uint64_t)d0 | ((uint64_t)d1 << 32);
                        uint64_t win = lo >> (off * 8);
                        if (off) win |= (uint64_t)d2 << (64 - off * 8);
                        uint64_t mask = win & M6;   // 6 bytes, surface bit stripped
                        if (mask) {
                            int bb = __ffsll((long long)mask) - 1;
                            label = (int)((win >> (bb & 56)) & 0x7f);
                            break;
                        }
                    }
                }
                p = label;
            }
            pv[b] = p;
        }
        pano.x = pv[0]; pano.y = pv[1]; pano.z = pv[2]; pano.w = pv[3];
        semv.x = slut[pv[0]]; semv.y = slut[pv[1]]; semv.z = slut[pv[2]]; semv.w = slut[pv[3]];
        int oi = (gx << 14) | (gy << 6) | zg;     // int4 index
        ((int4*)out_pano)[oi] = pano;
        ((int4*)out_sem)[oi] = semv;
    }
}

extern "C" void kernel_launch(void* const* d_in, const int* in_sizes, int n_in,
                              void* d_out, int out_size, void* d_ws, size_t ws_size,
                              hipStream_t stream) {
    const float* geo   = (const float*)d_in[0];
    const int*   inst  = (const int*)d_in[1];
    const int*   sem   = (const int*)d_in[2];
    const int*   ids2d = (const int*)d_in[3];
    const int    n2d   = in_sizes[3];

    char* ws = (char*)d_ws;
    int* counts16          = (int*)(ws);
    unsigned int* seenArr  = (unsigned int*)(ws + 32768);
    int* glut              = (int*)(ws + 65536);
    uint8_t* key8          = (uint8_t*)(ws + 69632);

    int* out_pano = (int*)d_out;
    int* out_sem  = out_pano + GRID_N;
    // key16 staged in d_out[0:32MB] -- consumed by k_prepB, then k_nn
    // overwrites all of d_out.
    uint16_t* key16 = (uint16_t*)d_out;

    hipMemsetAsync(counts16, 0, 32768, stream);
    k_prepA<<<PREP_BLOCKS, 256, 0, stream>>>(geo, inst, sem, key16);
    k_prepB<<<PREP_BLOCKS, 256, 0, stream>>>(key16, ids2d, n2d,
                                             counts16, seenArr, key8);
    k_luts<<<1, 512, 0, stream>>>(counts16, seenArr, ids2d, n2d, glut);
    dim3 g(32, 32);
    k_nn<<<g, 512, 0, stream>>>(key8, glut, out_pano, out_sem);
}